// Round 1
// baseline (46741.626 us; speedup 1.0000x reference)
//
#include <hip/hip_runtime.h>
#include <stdint.h>

#define TT 512
#define BB 64
#define II 256
#define HS 512          // H
#define HHALF 256       // HH
#define R4H 2048        // 4*H

// ---------------------------------------------------------------------------
// Phase 1: PG[t][r][b] = (b_ih[r]+b_hh[r]) + sum_k W_ih[r][k] * X[b][t][k]
// Simple LDS-tiled f32 GEMM. grid = (T, 32 r-tiles of 64), block = 256.
// ---------------------------------------------------------------------------
__global__ __launch_bounds__(256) void pregemm(
    const float* __restrict__ X,    // [B][T][I]
    const float* __restrict__ Wih,  // [4H][I]
    const float* __restrict__ bih,
    const float* __restrict__ bhh,
    float* __restrict__ PG)         // [T][4H][B]
{
  __shared__ __align__(16) float Xs[64][68];
  __shared__ __align__(16) float Ws[64][68];
  const int t = blockIdx.x;
  const int rbase = blockIdx.y * 64;
  const int tid = threadIdx.x;
  const int cg = tid & 15;   // b-tile: cols cg*4..+3
  const int rg = tid >> 4;   // r-tile: rows rg*4..+3

  float acc[4][4] = {};

  for (int k0 = 0; k0 < II; k0 += 64) {
    // stage X: Xs[kk][b] = X[b][t][k0+kk]
    {
      int b = tid >> 2, kq = tid & 3;
      const float* src = X + ((size_t)b * TT + t) * II + k0 + kq * 16;
      #pragma unroll
      for (int i = 0; i < 16; i += 4) {
        float4 v = *(const float4*)(src + i);
        int kk = kq * 16 + i;
        Xs[kk + 0][b] = v.x; Xs[kk + 1][b] = v.y;
        Xs[kk + 2][b] = v.z; Xs[kk + 3][b] = v.w;
      }
    }
    // stage W: Ws[kk][r] = Wih[rbase+r][k0+kk]
    {
      int r = tid >> 2, kq = tid & 3;
      const float* src = Wih + (size_t)(rbase + r) * II + k0 + kq * 16;
      #pragma unroll
      for (int i = 0; i < 16; i += 4) {
        float4 v = *(const float4*)(src + i);
        int kk = kq * 16 + i;
        Ws[kk + 0][r] = v.x; Ws[kk + 1][r] = v.y;
        Ws[kk + 2][r] = v.z; Ws[kk + 3][r] = v.w;
      }
    }
    __syncthreads();
    #pragma unroll 8
    for (int kk = 0; kk < 64; ++kk) {
      float4 a = *(const float4*)&Ws[kk][rg * 4];
      float4 x = *(const float4*)&Xs[kk][cg * 4];
      float av[4] = {a.x, a.y, a.z, a.w};
      float xv[4] = {x.x, x.y, x.z, x.w};
      #pragma unroll
      for (int i = 0; i < 4; ++i)
        #pragma unroll
        for (int j = 0; j < 4; ++j)
          acc[i][j] = fmaf(av[i], xv[j], acc[i][j]);
    }
    __syncthreads();
  }

  #pragma unroll
  for (int i = 0; i < 4; ++i) {
    int row = rbase + rg * 4 + i;
    float bias = bih[row] + bhh[row];
    float4 o;
    o.x = acc[i][0] + bias; o.y = acc[i][1] + bias;
    o.z = acc[i][2] + bias; o.w = acc[i][3] + bias;
    *(float4*)&PG[((size_t)t * R4H + row) * BB + cg * 4] = o;
  }
}

// ---------------------------------------------------------------------------
// init: hbuf[0][u][b] = memories[0][b][256+u]
// ---------------------------------------------------------------------------
__global__ void init_h(const float* __restrict__ mem, float* __restrict__ hbuf)
{
  int idx = blockIdx.x * 256 + threadIdx.x;
  if (idx < HS * BB) {
    int u = idx >> 6, b = idx & 63;
    hbuf[idx] = mem[(size_t)b * 1280 + 256 + u];
  }
}

// ---------------------------------------------------------------------------
// Persistent LSTM. grid = 256 WGs x 512 threads; WG g owns units {2g, 2g+1}.
// Per step: gates[8 rows][64 b] = PG[t] + W_hh_slice * h_prev, then the
// elementwise c/h update + running-cmax, one device-wide barrier per step.
// W slice lives in VGPRs (lane = k); per-k value extracted with v_readlane
// (SGPR operand of v_fma) -> no LDS-broadcast pipe pressure.
// ---------------------------------------------------------------------------
__device__ __forceinline__ float readlane_f(float v, int l) {
  return __int_as_float(__builtin_amdgcn_readlane(__float_as_int(v), l));
}

__device__ __forceinline__ void gridbar(unsigned* cnt, unsigned* gen, unsigned nwg)
{
  __threadfence();     // release all this thread's stores (device scope)
  __syncthreads();
  if (threadIdx.x == 0) {
    unsigned g = __hip_atomic_load(gen, __ATOMIC_ACQUIRE, __HIP_MEMORY_SCOPE_AGENT);
    unsigned a = __hip_atomic_fetch_add(cnt, 1u, __ATOMIC_ACQ_REL, __HIP_MEMORY_SCOPE_AGENT);
    if (a == nwg - 1u) {
      __hip_atomic_store(cnt, 0u, __ATOMIC_RELAXED, __HIP_MEMORY_SCOPE_AGENT);
      __hip_atomic_fetch_add(gen, 1u, __ATOMIC_RELEASE, __HIP_MEMORY_SCOPE_AGENT);
    } else {
      int spins = 0;
      while (__hip_atomic_load(gen, __ATOMIC_ACQUIRE, __HIP_MEMORY_SCOPE_AGENT) == g) {
        __builtin_amdgcn_s_sleep(2);
        if (++spins > (1 << 20)) break;   // failsafe: never hang the harness
      }
    }
  }
  __syncthreads();
  __threadfence();     // acquire side
}

__global__ __launch_bounds__(512) void lstm_persistent(
    const float* __restrict__ mem,   // [B][1280]
    const float* __restrict__ Whh,   // [4H][H]
    float* __restrict__ PG,          // [T][4H][B]; rows<512 overwritten with out vals
    float* __restrict__ hbuf,        // [2][H][B]
    float* __restrict__ outmem,      // [B][1280]
    unsigned* __restrict__ bar)      // {cnt, gen}
{
  const int g = blockIdx.x;
  const int u0 = g * 2;
  const int tid = threadIdx.x;
  const int w = tid >> 6;      // wave id = k-octant
  const int lane = tid & 63;

  __shared__ float part[8][64][9];
  __shared__ float gsum[8][64];

  // Preload W_hh slice into VGPRs: Wreg[r] = Whh[row(r)][w*64 + lane]
  float Wreg[8];
  #pragma unroll
  for (int r = 0; r < 8; ++r) {
    int q = r >> 1, du = r & 1;
    int row = q * HS + u0 + du;
    Wreg[r] = Whh[(size_t)row * HS + w * 64 + lane];
  }

  // per-(unit,batch) state for the elementwise threads (tid < 128)
  const int eu = u0 + (tid >> 6);  // valid for tid<128
  const int eb = lane;
  float c_st = 0.f, m_st = 0.f, h_last = 0.f;
  if (tid < 128) {
    c_st = mem[(size_t)eb * 1280 + 768 + eu];
    if (u0 < HHALF) m_st = mem[(size_t)eb * 1280 + eu];
  }

  const unsigned nwg = gridDim.x;
  const int rr = tid >> 6;                 // reduction row 0..7
  const int grow = (rr >> 1) * HS + u0 + (rr & 1);  // global gate row for rr

  for (int t = 0; t < TT; ++t) {
    const float* hcur = hbuf + (size_t)(t & 1) * HS * BB;
    // prefetch this thread's pre-gate value (hidden under the GEMM)
    float pg = PG[((size_t)t * R4H + grow) * BB + lane];

    // ---- recurrent GEMM over this wave's k-octant ----
    float acc[8] = {0, 0, 0, 0, 0, 0, 0, 0};
    const float* hp = hcur + (size_t)w * 64 * BB + lane;
    #pragma unroll 8
    for (int kk = 0; kk < 64; ++kk) {
      float h = hp[(size_t)kk * BB];
      #pragma unroll
      for (int r = 0; r < 8; ++r) {
        float wv = readlane_f(Wreg[r], kk);
        acc[r] = fmaf(wv, h, acc[r]);
      }
    }
    #pragma unroll
    for (int r = 0; r < 8; ++r) part[r][lane][w] = acc[r];
    __syncthreads();

    // ---- reduce 8 k-octant partials + pg ----
    float s = pg;
    #pragma unroll
    for (int ww = 0; ww < 8; ++ww) s += part[rr][lane][ww];
    gsum[rr][lane] = s;
    __syncthreads();

    // ---- elementwise LSTM cell + running cmax (tid < 128) ----
    if (tid < 128) {
      int du = tid >> 6;
      float gi = gsum[0 + du][eb];
      float gf = gsum[2 + du][eb];
      float gg = gsum[4 + du][eb];
      float go = gsum[6 + du][eb];
      float si = 1.f / (1.f + __expf(-gi));
      float sf = 1.f / (1.f + __expf(-gf));
      float so = 1.f / (1.f + __expf(-go));
      float tg = tanhf(gg);
      c_st = sf * c_st + si * tg;
      float hval = so * tanhf(c_st);
      h_last = hval;
      hbuf[(size_t)((t + 1) & 1) * HS * BB + (size_t)eu * BB + eb] = hval;
      float outv;
      if (u0 < HHALF) { m_st = fmaxf(m_st, hval); outv = m_st; }
      else            { outv = hval; }
      // stash output (pre-transpose) into PG[t][u][b] (already consumed)
      PG[((size_t)t * R4H + eu) * BB + eb] = outv;
    }

    gridbar(bar, bar + 1, nwg);
  }

  if (tid < 128) {
    outmem[(size_t)eb * 1280 + 256 + eu] = h_last;
    outmem[(size_t)eb * 1280 + 768 + eu] = c_st;
    if (u0 < HHALF) outmem[(size_t)eb * 1280 + eu] = m_st;
  }
}

// ---------------------------------------------------------------------------
// Phase 3: out[b][t][u] = PG[t][u][b]  (u < 512)
// ---------------------------------------------------------------------------
__global__ __launch_bounds__(256) void transpose_out(
    const float* __restrict__ PG, float* __restrict__ out)
{
  __shared__ __align__(16) float tileS[64][68];
  const int t = blockIdx.x;
  const int u0 = blockIdx.y * 64;
  const int tid = threadIdx.x;

  {
    int cg = tid & 15, rg = tid >> 4;
    const float* src = PG + (size_t)t * R4H * BB + (size_t)u0 * BB;
    #pragma unroll
    for (int i = 0; i < 4; ++i) {
      int u = rg * 4 + i;
      float4 v = *(const float4*)(src + (size_t)u * BB + cg * 4);
      *(float4*)&tileS[u][cg * 4] = v;
    }
  }
  __syncthreads();
  {
    int ug = tid & 15, bg = tid >> 4;
    #pragma unroll
    for (int i = 0; i < 4; ++i) {
      int b = bg * 4 + i;
      float4 o;
      o.x = tileS[ug * 4 + 0][b];
      o.y = tileS[ug * 4 + 1][b];
      o.z = tileS[ug * 4 + 2][b];
      o.w = tileS[ug * 4 + 3][b];
      *(float4*)&out[((size_t)b * TT + t) * HS + u0 + ug * 4] = o;
    }
  }
}

// ---------------------------------------------------------------------------
extern "C" void kernel_launch(void* const* d_in, const int* in_sizes, int n_in,
                              void* d_out, int out_size, void* d_ws, size_t ws_size,
                              hipStream_t stream)
{
  const float* X   = (const float*)d_in[0];  // input_tensor [B][T][I]
  const float* mem = (const float*)d_in[1];  // memories [1][B][1280]
  const float* Wih = (const float*)d_in[2];  // [2048][256]
  const float* Whh = (const float*)d_in[3];  // [2048][512]
  const float* bih = (const float*)d_in[4];
  const float* bhh = (const float*)d_in[5];

  float* out = (float*)d_out;                         // [B][T][H] then [B][1280]
  float* outmem = out + (size_t)BB * TT * HS;

  float* PG   = (float*)d_ws;                         // 512*2048*64 f32 = 256 MB
  float* hbuf = PG + (size_t)TT * R4H * BB;           // 2*512*64 f32
  unsigned* bar = (unsigned*)(hbuf + 2 * HS * BB);

  hipMemsetAsync(bar, 0, 2 * sizeof(unsigned), stream);
  init_h<<<dim3((HS * BB + 255) / 256), dim3(256), 0, stream>>>(mem, hbuf);
  pregemm<<<dim3(TT, 32), dim3(256), 0, stream>>>(X, Wih, bih, bhh, PG);
  lstm_persistent<<<dim3(256), dim3(512), 0, stream>>>(mem, Whh, PG, hbuf, outmem, bar);
  transpose_out<<<dim3(TT, 8), dim3(256), 0, stream>>>(PG, out);
}

// Round 6
// 4237.046 us; speedup vs baseline: 11.0317x; 11.0317x over previous
//
#include <hip/hip_runtime.h>
#include <stdint.h>

#define TT 512
#define BB 64
#define II 256
#define HS 512          // H
#define HHALF 256       // HH
#define R4H 2048        // 4*H

// ---------------------------------------------------------------------------
// Phase 1: PG[t][r][b] = (b_ih[r]+b_hh[r]) + sum_k W_ih[r][k] * X[b][t][k]
// ---------------------------------------------------------------------------
__global__ __launch_bounds__(256) void pregemm(
    const float* __restrict__ X,    // [B][T][I]
    const float* __restrict__ Wih,  // [4H][I]
    const float* __restrict__ bih,
    const float* __restrict__ bhh,
    float* __restrict__ PG)         // [T][4H][B]
{
  __shared__ __align__(16) float Xs[64][68];
  __shared__ __align__(16) float Ws[64][68];
  const int t = blockIdx.x;
  const int rbase = blockIdx.y * 64;
  const int tid = threadIdx.x;
  const int cg = tid & 15;
  const int rg = tid >> 4;

  float acc[4][4] = {};

  for (int k0 = 0; k0 < II; k0 += 64) {
    {
      int b = tid >> 2, kq = tid & 3;
      const float* src = X + ((size_t)b * TT + t) * II + k0 + kq * 16;
      #pragma unroll
      for (int i = 0; i < 16; i += 4) {
        float4 v = *(const float4*)(src + i);
        int kk = kq * 16 + i;
        Xs[kk + 0][b] = v.x; Xs[kk + 1][b] = v.y;
        Xs[kk + 2][b] = v.z; Xs[kk + 3][b] = v.w;
      }
    }
    {
      int r = tid >> 2, kq = tid & 3;
      const float* src = Wih + (size_t)(rbase + r) * II + k0 + kq * 16;
      #pragma unroll
      for (int i = 0; i < 16; i += 4) {
        float4 v = *(const float4*)(src + i);
        int kk = kq * 16 + i;
        Ws[kk + 0][r] = v.x; Ws[kk + 1][r] = v.y;
        Ws[kk + 2][r] = v.z; Ws[kk + 3][r] = v.w;
      }
    }
    __syncthreads();
    #pragma unroll 8
    for (int kk = 0; kk < 64; ++kk) {
      float4 a = *(const float4*)&Ws[kk][rg * 4];
      float4 x = *(const float4*)&Xs[kk][cg * 4];
      float av[4] = {a.x, a.y, a.z, a.w};
      float xv[4] = {x.x, x.y, x.z, x.w};
      #pragma unroll
      for (int i = 0; i < 4; ++i)
        #pragma unroll
        for (int j = 0; j < 4; ++j)
          acc[i][j] = fmaf(av[i], xv[j], acc[i][j]);
    }
    __syncthreads();
  }

  #pragma unroll
  for (int i = 0; i < 4; ++i) {
    int row = rbase + rg * 4 + i;
    float bias = bih[row] + bhh[row];
    float4 o;
    o.x = acc[i][0] + bias; o.y = acc[i][1] + bias;
    o.z = acc[i][2] + bias; o.w = acc[i][3] + bias;
    *(float4*)&PG[((size_t)t * R4H + row) * BB + cg * 4] = o;
  }
}

// ---------------------------------------------------------------------------
__global__ void init_h(const float* __restrict__ mem, float* __restrict__ hbuf)
{
  int idx = blockIdx.x * 256 + threadIdx.x;
  if (idx < HS * BB) {
    int u = idx >> 6, b = idx & 63;
    hbuf[idx] = mem[(size_t)b * 1280 + 256 + u];
  }
}

// ---------------------------------------------------------------------------
// Cross-XCD h hand-off:
//  - store side: relaxed agent-scope atomic EXCHANGE (RMW). RMWs are
//    performed AT the device coherence point (Infinity Cache), so the
//    vmcnt(0) ack guarantees the value is globally visible before the
//    barrier-arrival RMW can issue. (R3 used a plain sc1 store; its ack may
//    come from the local XCD L2 while the write-through is still in flight,
//    letting the barrier RMW overtake the data -> stale reads. That was the
//    post-timing divergence.)
//  - load side: relaxed agent-scope atomic load (sc1) bypasses the stale
//    per-CU L1 / per-XCD L2 and reads the coherence point.
//  - RELAXED everywhere => no buffer_wbl2/buffer_inv sweeps (the 91 us/step
//    cost that killed R1).
// ---------------------------------------------------------------------------
__device__ __forceinline__ void store_coh(float* p, float v) {
  (void)__hip_atomic_exchange((int*)p, __float_as_int(v), __ATOMIC_RELAXED,
                              __HIP_MEMORY_SCOPE_AGENT);
}
__device__ __forceinline__ float load_coh(const float* p) {
  return __int_as_float(__hip_atomic_load((const int*)p, __ATOMIC_RELAXED,
                                          __HIP_MEMORY_SCOPE_AGENT));
}
__device__ __forceinline__ float readlane_f(float v, int l) {
  return __int_as_float(__builtin_amdgcn_readlane(__float_as_int(v), l));
}

// ---------------------------------------------------------------------------
// Persistent LSTM. grid = 256 WGs x 512 threads; WG g owns units {2g, 2g+1}.
// Per-step device barrier: hierarchical monotonic counters (8 group counters
// on separate cachelines + 1 second level + gen), all RELAXED agent RMWs.
// ---------------------------------------------------------------------------
__global__ __launch_bounds__(512) void lstm_persistent(
    const float* __restrict__ mem,   // [B][1280]
    const float* __restrict__ Whh,   // [4H][H]
    float* __restrict__ PG,          // [T][4H][B]
    float* __restrict__ hbuf,        // [2][H][B]
    float* __restrict__ outmem,      // [B][1280]
    unsigned* __restrict__ bar)      // grpcnt[8]@stride64, cnt2@1024, gen@1088
{
  const int g = blockIdx.x;
  const int u0 = g * 2;
  const int tid = threadIdx.x;
  const int w = tid >> 6;      // wave id = k-octant
  const int lane = tid & 63;

  __shared__ float part[8][64][9];
  __shared__ float gsum[8][64];

  unsigned* grpcnt = bar + (g >> 5) * 64;
  unsigned* cnt2   = bar + 1024;
  unsigned* gen    = bar + 1088;

  // Preload W_hh slice: Wreg[r] = Whh[row(r)][w*64 + lane]
  float Wreg[8];
  #pragma unroll
  for (int r = 0; r < 8; ++r) {
    int q = r >> 1, du = r & 1;
    int row = q * HS + u0 + du;
    Wreg[r] = Whh[(size_t)row * HS + w * 64 + lane];
  }

  const int eu = u0 + (tid >> 6);  // valid for tid<128
  const int eb = lane;
  float c_st = 0.f, m_st = 0.f, h_last = 0.f;
  if (tid < 128) {
    c_st = mem[(size_t)eb * 1280 + 768 + eu];
    if (u0 < HHALF) m_st = mem[(size_t)eb * 1280 + eu];
  }

  const int rr = tid >> 6;
  const int grow = (rr >> 1) * HS + u0 + (rr & 1);

  for (int t = 0; t < TT; ++t) {
    const float* hcur = hbuf + (size_t)(t & 1) * HS * BB;
    float pg = PG[((size_t)t * R4H + grow) * BB + lane];

    // ---- prefetch this wave's h block (coherent loads, all in flight) ----
    const float* hp = hcur + (size_t)w * 64 * BB + lane;
    float hreg[64];
    #pragma unroll
    for (int kk = 0; kk < 64; ++kk) hreg[kk] = load_coh(hp + (size_t)kk * BB);

    // ---- recurrent GEMM over this wave's k-octant ----
    float acc[8] = {0, 0, 0, 0, 0, 0, 0, 0};
    #pragma unroll
    for (int kk = 0; kk < 64; ++kk) {
      float h = hreg[kk];
      #pragma unroll
      for (int r = 0; r < 8; ++r) {
        float wv = readlane_f(Wreg[r], kk);   // kk is compile-time constant
        acc[r] = fmaf(wv, h, acc[r]);
      }
    }
    #pragma unroll
    for (int r = 0; r < 8; ++r) part[r][lane][w] = acc[r];
    __syncthreads();

    // ---- reduce 8 k-octant partials + pg ----
    float s = pg;
    #pragma unroll
    for (int ww = 0; ww < 8; ++ww) s += part[rr][lane][ww];
    gsum[rr][lane] = s;
    __syncthreads();

    // ---- elementwise LSTM cell + running cmax (tid < 128) ----
    if (tid < 128) {
      int du = tid >> 6;
      float gi = gsum[0 + du][eb];
      float gf = gsum[2 + du][eb];
      float gg = gsum[4 + du][eb];
      float go = gsum[6 + du][eb];
      float si = 1.f / (1.f + __expf(-gi));
      float sf = 1.f / (1.f + __expf(-gf));
      float so = 1.f / (1.f + __expf(-go));
      float tg = tanhf(gg);
      c_st = sf * c_st + si * tg;
      float hval = so * tanhf(c_st);
      h_last = hval;
      store_coh(&hbuf[(size_t)((t + 1) & 1) * HS * BB + (size_t)eu * BB + eb], hval);
      float outv;
      if (u0 < HHALF) { m_st = fmaxf(m_st, hval); outv = m_st; }
      else            { outv = hval; }
      PG[((size_t)t * R4H + eu) * BB + eb] = outv;  // stash (same-WG rows only)
    }

    // ---- device barrier: release = vmcnt(0) on the exchange h-stores ----
    asm volatile("s_waitcnt vmcnt(0)" ::: "memory");
    __syncthreads();
    if (tid == 0) {
      unsigned tgt1 = 32u * (unsigned)(t + 1);
      unsigned a = __hip_atomic_fetch_add(grpcnt, 1u, __ATOMIC_RELAXED,
                                          __HIP_MEMORY_SCOPE_AGENT);
      if (a == tgt1 - 1u) {
        unsigned b2 = __hip_atomic_fetch_add(cnt2, 1u, __ATOMIC_RELAXED,
                                             __HIP_MEMORY_SCOPE_AGENT);
        if (b2 == 8u * (unsigned)(t + 1) - 1u)
          (void)__hip_atomic_exchange(gen, (unsigned)(t + 1), __ATOMIC_RELAXED,
                                      __HIP_MEMORY_SCOPE_AGENT);
      }
      // failsafe cap: fast wrong-answer instead of a container-killing hang.
      // Expected wait is a few microseconds; cap is ~4 orders above that.
      int spins = 0;
      while (__hip_atomic_load(gen, __ATOMIC_RELAXED,
                               __HIP_MEMORY_SCOPE_AGENT) < (unsigned)(t + 1)) {
        __builtin_amdgcn_s_sleep(2);
        if (++spins > (1 << 16)) break;
      }
    }
    __syncthreads();
  }

  if (tid < 128) {
    outmem[(size_t)eb * 1280 + 256 + eu] = h_last;
    outmem[(size_t)eb * 1280 + 768 + eu] = c_st;
    if (u0 < HHALF) outmem[(size_t)eb * 1280 + eu] = m_st;
  }
}

// ---------------------------------------------------------------------------
// Phase 3: out[b][t][u] = PG[t][u][b]  (u < 512)
// ---------------------------------------------------------------------------
__global__ __launch_bounds__(256) void transpose_out(
    const float* __restrict__ PG, float* __restrict__ out)
{
  __shared__ __align__(16) float tileS[64][68];
  const int t = blockIdx.x;
  const int u0 = blockIdx.y * 64;
  const int tid = threadIdx.x;

  {
    int cg = tid & 15, rg = tid >> 4;
    const float* src = PG + (size_t)t * R4H * BB + (size_t)u0 * BB;
    #pragma unroll
    for (int i = 0; i < 4; ++i) {
      int u = rg * 4 + i;
      float4 v = *(const float4*)(src + (size_t)u * BB + cg * 4);
      *(float4*)&tileS[u][cg * 4] = v;
    }
  }
  __syncthreads();
  {
    int ug = tid & 15, bg = tid >> 4;
    #pragma unroll
    for (int i = 0; i < 4; ++i) {
      int b = bg * 4 + i;
      float4 o;
      o.x = tileS[ug * 4 + 0][b];
      o.y = tileS[ug * 4 + 1][b];
      o.z = tileS[ug * 4 + 2][b];
      o.w = tileS[ug * 4 + 3][b];
      *(float4*)&out[((size_t)b * TT + t) * HS + u0 + ug * 4] = o;
    }
  }
}

// ---------------------------------------------------------------------------
extern "C" void kernel_launch(void* const* d_in, const int* in_sizes, int n_in,
                              void* d_out, int out_size, void* d_ws, size_t ws_size,
                              hipStream_t stream)
{
  const float* X   = (const float*)d_in[0];
  const float* mem = (const float*)d_in[1];
  const float* Wih = (const float*)d_in[2];
  const float* Whh = (const float*)d_in[3];
  const float* bih = (const float*)d_in[4];
  const float* bhh = (const float*)d_in[5];

  float* out = (float*)d_out;
  float* outmem = out + (size_t)BB * TT * HS;

  float* PG   = (float*)d_ws;                 // 512*2048*64 f32 = 256 MB
  float* hbuf = PG + (size_t)TT * R4H * BB;   // 2*512*64 f32
  unsigned* bar = (unsigned*)(hbuf + 2 * HS * BB);  // 2048 u32

  hipMemsetAsync(bar, 0, 2048 * sizeof(unsigned), stream);
  init_h<<<dim3((HS * BB + 255) / 256), dim3(256), 0, stream>>>(mem, hbuf);
  pregemm<<<dim3(TT, 32), dim3(256), 0, stream>>>(X, Wih, bih, bhh, PG);
  lstm_persistent<<<dim3(256), dim3(512), 0, stream>>>(mem, Whh, PG, hbuf, outmem, bar);
  transpose_out<<<dim3(TT, 8), dim3(256), 0, stream>>>(PG, out);
}